// Round 6
// baseline (9584.110 us; speedup 1.0000x reference)
//
#include <hip/hip_runtime.h>
#include <cstdint>
#include <cstddef>

namespace {

constexpr int H    = 300;
constexpr int G4   = 1200;   // 4*H
constexpr int B    = 128;
constexpr int T    = 512;
constexpr int NVOC = 2514;

// ---------------------------------------------------------------------------
// Tiled fp32 GEMM (unchanged; ~2.2 ms total, future MFMA target)
// ---------------------------------------------------------------------------
template<int AMODE, bool HASB2>
__global__ __launch_bounds__(256)
void gemm_tn(const float* __restrict__ A, const float* __restrict__ W,
             const float* __restrict__ b1, const float* __restrict__ b2,
             const int* __restrict__ tok, float* __restrict__ out, int N)
{
    constexpr int K = 300;
    __shared__ __align__(16) float as[8][128];
    __shared__ __align__(16) float bs[8][128];

    const int tid = threadIdx.x;
    const int tx = tid & 15, ty = tid >> 4;
    const int m0 = blockIdx.y * 128;
    const int n0 = blockIdx.x * 128;
    const int rl  = tid >> 1;
    const int kk0 = (tid & 1) * 4;

    const int m = m0 + rl;
    int arow;
    if (AMODE == 0) {
        arow = m;
    } else {
        const int q = ((m & 127) << 9) + (m >> 7);
        arow = (AMODE == 1) ? tok[q] : q;
    }
    const float* aptr = A + (size_t)arow * K;
    const int nrow = n0 + rl;
    const float* wptr = W + (size_t)nrow * K;
    const bool nvalid = (nrow < N);

    float acc[8][8];
#pragma unroll
    for (int i = 0; i < 8; ++i)
#pragma unroll
        for (int j = 0; j < 8; ++j) acc[i][j] = 0.f;

    for (int k0 = 0; k0 < K; k0 += 8) {
        float4 av = make_float4(0.f, 0.f, 0.f, 0.f);
        float4 bv = make_float4(0.f, 0.f, 0.f, 0.f);
        const bool kv = (k0 + kk0 < K);
        if (kv)           av = *(const float4*)(aptr + k0 + kk0);
        if (kv && nvalid) bv = *(const float4*)(wptr + k0 + kk0);
        __syncthreads();
        as[kk0+0][rl] = av.x; as[kk0+1][rl] = av.y; as[kk0+2][rl] = av.z; as[kk0+3][rl] = av.w;
        bs[kk0+0][rl] = bv.x; bs[kk0+1][rl] = bv.y; bs[kk0+2][rl] = bv.z; bs[kk0+3][rl] = bv.w;
        __syncthreads();
#pragma unroll
        for (int kk = 0; kk < 8; ++kk) {
            float4 a0 = *(const float4*)&as[kk][ty*8];
            float4 a1 = *(const float4*)&as[kk][ty*8+4];
            float4 c0 = *(const float4*)&bs[kk][tx*8];
            float4 c1 = *(const float4*)&bs[kk][tx*8+4];
            float a[8] = {a0.x,a0.y,a0.z,a0.w,a1.x,a1.y,a1.z,a1.w};
            float b[8] = {c0.x,c0.y,c0.z,c0.w,c1.x,c1.y,c1.z,c1.w};
#pragma unroll
            for (int i = 0; i < 8; ++i)
#pragma unroll
                for (int j = 0; j < 8; ++j)
                    acc[i][j] = fmaf(a[i], b[j], acc[i][j]);
        }
    }

    float bias[8];
#pragma unroll
    for (int j = 0; j < 8; ++j) {
        const int n = n0 + tx*8 + j;
        float v = 0.f;
        if (n < N) { v = b1[n]; if (HASB2) v += b2[n]; }
        bias[j] = v;
    }
#pragma unroll
    for (int i = 0; i < 8; ++i) {
        const int mi = m0 + ty*8 + i;
        float* orow = out + (size_t)mi * N + n0 + tx*8;
#pragma unroll
        for (int j = 0; j < 8; j += 2) {
            const int n = n0 + tx*8 + j;
            if (n + 1 < N) {
                *(float2*)(orow + j) = make_float2(acc[i][j] + bias[j],
                                                   acc[i][j+1] + bias[j+1]);
            } else if (n < N) {
                orow[j] = acc[i][j] + bias[j];
            }
        }
    }
}

// ---------------------------------------------------------------------------
// Sentinel fill (data-as-flag protocol)
// ---------------------------------------------------------------------------
constexpr unsigned SENT = 0x7FB00F0Fu;   // quiet NaN payload; h in (-1,1) never NaN

__global__ __launch_bounds__(256)
void sentinel_fill(uint4* __restrict__ p, size_t n4)
{
    const uint4 s = make_uint4(SENT, SENT, SENT, SENT);
    size_t i = (size_t)blockIdx.x * blockDim.x + threadIdx.x;
    const size_t stride = (size_t)gridDim.x * blockDim.x;
    for (; i < n4; i += stride) p[i] = s;
}

// ---------------------------------------------------------------------------
// LSTM recurrence v6 — v5 (MFMA, W-in-VGPRs) + two sync fixes:
//  (1) BATCHED poll scan: round 5's scan was 12 *serialized* L3 round trips
//      (load->check->consume chains, ~3.5 us); now all pending loads issue
//      back-to-back into temps, then get checked -> scan ~ 1 RT (~0.4 us).
//  (2) XCD-affine mapping: bg = blockIdx%16, hg = blockIdx/16. Under
//      round-robin dispatch (XCD = blockIdx%8), all 15 blocks of a batch
//      group (stride 16 apart) land on ONE XCD -> h exchange may be served
//      XCD-locally. Perf heuristic only; correctness never depends on it.
// ---------------------------------------------------------------------------
constexpr int HGC = 15;
constexpr int BGC = 16;
constexpr int NWG = HGC * BGC;   // 240

typedef __attribute__((ext_vector_type(8))) short  short8;
typedef __attribute__((ext_vector_type(4))) float  f32x4;

__device__ __forceinline__ float sigm(float x)     { return 1.f / (1.f + __expf(-x)); }
__device__ __forceinline__ float tanhfast(float x) { return 1.f - 2.f / (__expf(2.f*x) + 1.f); }

__device__ __forceinline__ unsigned short bf16_rn(float f) {
    unsigned u = __float_as_uint(f);
    u += 0x7FFFu + ((u >> 16) & 1u);
    return (unsigned short)(u >> 16);
}
__device__ __forceinline__ float bf16_f(unsigned short s) {
    return __uint_as_float(((unsigned)s) << 16);
}
__device__ __forceinline__ unsigned pack2(unsigned short lo16, unsigned short hi16) {
    return (unsigned)lo16 | ((unsigned)hi16 << 16);
}

// A-fragment LDS layout, per parity: [kt 0..9][half 0..1][kg 0..3][m 0..15][16B]
constexpr int APAR = 20480;

template<int NT0, int NTN, bool ISW0>
__device__ void compute_wave(int lane, int hg, int bg,
                             const float* __restrict__ xg,
                             const float* __restrict__ Whh,
                             float* __restrict__ h_all,
                             unsigned char (*Abuf)[APAR],
                             float (*gd)[80], int* lflags)
{
    const int kg = lane >> 4, mm = lane & 15;

    // ---- one-time: B fragments (hi/lo bf16) into registers ----
    short8 bh[10][NTN], bl[10][NTN];
#pragma unroll
    for (int kt = 0; kt < 10; ++kt) {
#pragma unroll
        for (int j = 0; j < NTN; ++j) {
            const int n    = (NT0 + j) * 16 + mm;
            const int grow = (n / 20) * H + hg * 20 + (n % 20);
            const int k0   = kt * 32 + kg * 8;
            short8 hi, lo;
#pragma unroll
            for (int q = 0; q < 8; ++q) {
                const int k = k0 + q;
                const float v = (k < H) ? Whh[(size_t)grow * H + k] : 0.f;
                const unsigned short h16 = bf16_rn(v);
                hi[q] = (short)h16;
                lo[q] = (short)bf16_rn(v - bf16_f(h16));
            }
            bh[kt][j] = hi; bl[kt][j] = lo;
        }
    }

    float cst[4] = {0.f, 0.f, 0.f, 0.f};

    for (int t = 0; t < T; ++t) {
        // xg prefetch (overlaps the flag wait)
        float xv[4][4];
        if (ISW0 && lane < 40) {
#pragma unroll
            for (int r = 0; r < 4; ++r) {
                const int idx = lane + 40 * r, b = idx / 20, l = idx % 20;
                const float* xb = xg + ((size_t)t * B + bg * 8 + b) * G4 + hg * 20 + l;
#pragma unroll
                for (int g = 0; g < 4; ++g) xv[r][g] = xb[g * H];
            }
        }

        if (t > 0) {
            while (__hip_atomic_load(&lflags[0], __ATOMIC_ACQUIRE,
                                     __HIP_MEMORY_SCOPE_WORKGROUP) < t ||
                   __hip_atomic_load(&lflags[1], __ATOMIC_ACQUIRE,
                                     __HIP_MEMORY_SCOPE_WORKGROUP) < t) {}
        }
        const unsigned char* Ab = Abuf[t & 1];

        f32x4 D[NTN];
#pragma unroll
        for (int j = 0; j < NTN; ++j) D[j] = (f32x4){0.f, 0.f, 0.f, 0.f};

#pragma unroll
        for (int kt = 0; kt < 10; ++kt) {
            const short8 ah = *(const short8*)(Ab + ((kt*2+0)*4 + kg)*256 + mm*16);
            const short8 al = *(const short8*)(Ab + ((kt*2+1)*4 + kg)*256 + mm*16);
#pragma unroll
            for (int j = 0; j < NTN; ++j) {
                D[j] = __builtin_amdgcn_mfma_f32_16x16x32_bf16(ah, bh[kt][j], D[j], 0, 0, 0);
                D[j] = __builtin_amdgcn_mfma_f32_16x16x32_bf16(al, bh[kt][j], D[j], 0, 0, 0);
                D[j] = __builtin_amdgcn_mfma_f32_16x16x32_bf16(ah, bl[kt][j], D[j], 0, 0, 0);
            }
        }

        if (lane < 32) {
#pragma unroll
            for (int j = 0; j < NTN; ++j)
#pragma unroll
                for (int r = 0; r < 4; ++r)
                    gd[(lane >> 4) * 4 + r][(NT0 + j) * 16 + mm] = D[j][r];
        }

        if (!ISW0) {
            __hip_atomic_store(&lflags[2], t + 1, __ATOMIC_RELEASE,
                               __HIP_MEMORY_SCOPE_WORKGROUP);
        } else {
            while (__hip_atomic_load(&lflags[2], __ATOMIC_ACQUIRE,
                                     __HIP_MEMORY_SCOPE_WORKGROUP) < t + 1) {}
            if (lane < 40) {
#pragma unroll
                for (int r = 0; r < 4; ++r) {
                    const int idx = lane + 40 * r, b = idx / 20, l = idx % 20;
                    const float gi = xv[r][0] + gd[b][     l];
                    const float gf = xv[r][1] + gd[b][20 + l];
                    const float gz = xv[r][2] + gd[b][40 + l];
                    const float go = xv[r][3] + gd[b][60 + l];
                    const float iG = sigm(gi), fG = sigm(gf);
                    const float zG = tanhfast(gz), oG = sigm(go);
                    cst[r] = fmaf(fG, cst[r], iG * zG);
                    const float hv = oG * tanhfast(cst[r]);
                    __hip_atomic_store(h_all + ((size_t)(bg*8 + b) * T + t) * H + hg*20 + l,
                                       hv, __ATOMIC_RELAXED, __HIP_MEMORY_SCOPE_AGENT);
                }
            }
        }
    }
}

__device__ void poller_wave(int pw, int lane, int bg,
                            const float* __restrict__ h_all,
                            unsigned char (*Abuf)[APAR], int* lflags)
{
    const int pl = pw * 64 + lane;         // 0..127
    const float* qbase[3]; int offh[3], offl[3]; unsigned pend0 = 0; bool qok[3];
#pragma unroll
    for (int q = 0; q < 3; ++q) {
        const int s = pl + 128 * q;
        qok[q] = (s < 304);
        if (qok[q]) {
            const int b = s / 38, kq = s % 38;
            qbase[q] = h_all + (size_t)(bg*8 + b) * T * H + kq * 8;
            const int kt = kq >> 2, kgq = kq & 3;
            offh[q] = ((kt*2 + 0)*4 + kgq)*256 + b*16;
            offl[q] = ((kt*2 + 1)*4 + kgq)*256 + b*16;
            pend0 |= ((kq < 37) ? 0xFu : 0x3u) << (4*q);
        } else { qbase[q] = h_all; offh[q] = offl[q] = 0; }
    }

    for (int pt = 1; pt < T; ++pt) {
        float v[3][8];
#pragma unroll
        for (int q = 0; q < 3; ++q)
#pragma unroll
            for (int e = 0; e < 8; ++e) v[q][e] = 0.f;

        unsigned pend = pend0;
        const size_t toff = (size_t)(pt - 1) * H;
        while (__any(pend != 0)) {
            // Phase 1: issue ALL pending loads back-to-back (no consumption
            // between loads -> they pipeline; scan ~ 1 L3 RT, not 12).
            unsigned long long w[3][4];
#pragma unroll
            for (int q = 0; q < 3; ++q)
#pragma unroll
                for (int j2 = 0; j2 < 4; ++j2)
                    if (pend & (1u << (4*q + j2)))
                        w[q][j2] = __hip_atomic_load(
                            (const unsigned long long*)(qbase[q] + toff) + j2,
                            __ATOMIC_RELAXED, __HIP_MEMORY_SCOPE_AGENT);
            // Phase 2: check + consume
#pragma unroll
            for (int q = 0; q < 3; ++q)
#pragma unroll
                for (int j2 = 0; j2 < 4; ++j2) {
                    const unsigned bit = 1u << (4*q + j2);
                    if (pend & bit) {
                        const unsigned long long x = w[q][j2];
                        if ((unsigned)x != SENT && (unsigned)(x >> 32) != SENT) {
                            v[q][2*j2]   = __uint_as_float((unsigned)x);
                            v[q][2*j2+1] = __uint_as_float((unsigned)(x >> 32));
                            pend &= ~bit;
                        }
                    }
                }
        }

        unsigned char* Ap = Abuf[pt & 1];
#pragma unroll
        for (int q = 0; q < 3; ++q) {
            if (qok[q]) {
                unsigned short h16[8]; uint4 hi, lo;
#pragma unroll
                for (int e = 0; e < 8; ++e) h16[e] = bf16_rn(v[q][e]);
                hi.x = pack2(h16[0], h16[1]); hi.y = pack2(h16[2], h16[3]);
                hi.z = pack2(h16[4], h16[5]); hi.w = pack2(h16[6], h16[7]);
                unsigned short l16[8];
#pragma unroll
                for (int e = 0; e < 8; ++e)
                    l16[e] = bf16_rn(v[q][e] - bf16_f(h16[e]));
                lo.x = pack2(l16[0], l16[1]); lo.y = pack2(l16[2], l16[3]);
                lo.z = pack2(l16[4], l16[5]); lo.w = pack2(l16[6], l16[7]);
                *(uint4*)(Ap + offh[q]) = hi;
                *(uint4*)(Ap + offl[q]) = lo;
            }
        }
        if (lane == 0)
            __hip_atomic_store(&lflags[pw], pt, __ATOMIC_RELEASE,
                               __HIP_MEMORY_SCOPE_WORKGROUP);
    }
}

__global__ __launch_bounds__(256, 1)
void lstm_mfma_k(const float* __restrict__ xg, const float* __restrict__ Whh,
                 float* __restrict__ h_all)
{
    __shared__ __align__(16) unsigned char Abuf[2][APAR];   // 40 KiB
    __shared__ __align__(16) float gd[8][80];
    __shared__ int lflags[16];

    const int tid = threadIdx.x, wv = tid >> 6, lane = tid & 63;
    // XCD-affine: bg's 15 blocks are blockIdx ≡ bg (mod 16) -> same XCD
    // under round-robin (%8) dispatch. Perf heuristic only.
    const int hg = blockIdx.x / BGC, bg = blockIdx.x % BGC;

    for (int i = tid; i < 2 * APAR / 16; i += 256)
        ((uint4*)Abuf)[i] = make_uint4(0, 0, 0, 0);
    if (tid < 16) lflags[tid] = 0;
    __syncthreads();

    if      (wv == 0) compute_wave<0, 3, true >(lane, hg, bg, xg, Whh, h_all, Abuf, gd, lflags);
    else if (wv == 1) compute_wave<3, 2, false>(lane, hg, bg, xg, Whh, h_all, Abuf, gd, lflags);
    else              poller_wave(wv - 2, lane, bg, h_all, Abuf, lflags);
}

} // anonymous namespace

// ---------------------------------------------------------------------------
extern "C" void kernel_launch(void* const* d_in, const int* in_sizes, int n_in,
                              void* d_out, int out_size, void* d_ws, size_t ws_size,
                              hipStream_t stream)
{
    const int*   x    = (const int*)  d_in[0];
    const float* emb  = (const float*)d_in[1];
    const float* Wih0 = (const float*)d_in[2];
    const float* Whh0 = (const float*)d_in[3];
    const float* bih0 = (const float*)d_in[4];
    const float* bhh0 = (const float*)d_in[5];
    const float* Wih1 = (const float*)d_in[6];
    const float* Whh1 = (const float*)d_in[7];
    const float* bih1 = (const float*)d_in[8];
    const float* bhh1 = (const float*)d_in[9];
    const float* Wout = (const float*)d_in[10];
    const float* bout = (const float*)d_in[11];

    float* out = (float*)d_out;
    // xg [T][B][4H] fp32 (315 MB) aliases the output buffer (659 MB): fully
    // consumed before the final GEMM overwrites d_out.
    float* xg = (float*)d_out;
    float* h1 = (float*)d_ws;                       // [B][T][H] fp32, 78.6 MB
    float* h2 = h1 + (size_t)B * T * H;             // 78.6 MB

    // sentinel-fill both h buffers (data-as-flag protocol)
    const size_t nh = 2 * (size_t)B * T * H;
    sentinel_fill<<<dim3(2048), dim3(256), 0, stream>>>((uint4*)h1, nh / 4);

    const dim3 blk(256);
    // L0 input projection (embedding gather fused)
    gemm_tn<1, true ><<<dim3(10, 512), blk, 0, stream>>>(emb, Wih0, bih0, bhh0, x, xg, G4);
    // L0 recurrence
    lstm_mfma_k<<<dim3(NWG), blk, 0, stream>>>(xg, Whh0, h1);
    // L1 input projection ([b][t] -> [t][b] permute fused)
    gemm_tn<2, true ><<<dim3(10, 512), blk, 0, stream>>>(h1, Wih1, bih1, bhh1, nullptr, xg, G4);
    // L1 recurrence
    lstm_mfma_k<<<dim3(NWG), blk, 0, stream>>>(xg, Whh1, h2);
    // output projection -> logits [b*T+t][NVOC]
    gemm_tn<0, false><<<dim3(20, 512), blk, 0, stream>>>(h2, Wout, bout, nullptr, nullptr, out, NVOC);
}

// Round 7
// 7352.269 us; speedup vs baseline: 1.3036x; 1.3036x over previous
//
#include <hip/hip_runtime.h>
#include <cstdint>
#include <cstddef>

namespace {

constexpr int H    = 300;
constexpr int G4   = 1200;   // 4*H
constexpr int B    = 128;
constexpr int T    = 512;
constexpr int NVOC = 2514;

typedef __attribute__((ext_vector_type(8))) short  short8;
typedef __attribute__((ext_vector_type(4))) float  f32x4;

__device__ __forceinline__ float sigm(float x)     { return 1.f / (1.f + __expf(-x)); }
__device__ __forceinline__ float tanhfast(float x) { return 1.f - 2.f / (__expf(2.f*x) + 1.f); }

__device__ __forceinline__ unsigned short bf16_rn(float f) {
    unsigned u = __float_as_uint(f);
    u += 0x7FFFu + ((u >> 16) & 1u);
    return (unsigned short)(u >> 16);
}
__device__ __forceinline__ float bf16_f(unsigned short s) {
    return __uint_as_float(((unsigned)s) << 16);
}
__device__ __forceinline__ unsigned pack2(unsigned short lo16, unsigned short hi16) {
    return (unsigned)lo16 | ((unsigned)hi16 << 16);
}

// ---------------------------------------------------------------------------
// MFMA split-precision GEMM: out[m][n] = A[row(m)][0:300] . W[n][0:300] + bias
// A,W fp32; internally A=Ah+Al, W=Wh+Wl (bf16); C = Ah*Wh + Al*Wh + Ah*Wl
// (lo*lo dropped, ~2^-18 rel). Tile 128x128, K-chunks of 32 (10 chunks,
// K=300 zero-padded). 4 waves, each computes a 64x64 quadrant via 4x4
// 16x16x32 MFMA frags. fp32->hi/lo conversion fused into LDS staging.
// AMODE 0: row = m;  1: row = tok[(m&127)*512 + (m>>7)] (embedding gather);
// 2: row = (m&127)*512 + (m>>7)  ([b,t] <-> [t,b] permute).
// ---------------------------------------------------------------------------
template<int AMODE, bool HASB2>
__global__ __launch_bounds__(256)
void gemm_mfma(const float* __restrict__ A, const float* __restrict__ W,
               const float* __restrict__ b1, const float* __restrict__ b2,
               const int* __restrict__ tok, float* __restrict__ out, int N)
{
    // pitch 40 shorts (80 B): bank index (row*20 + kg*4)%32 -> 2-way (free)
    __shared__ __align__(16) unsigned short Ah[128][40], Al[128][40];
    __shared__ __align__(16) unsigned short Wh[128][40], Wl[128][40];

    const int tid = threadIdx.x;
    const int m0 = blockIdx.y * 128, n0 = blockIdx.x * 128;

    // staging: thread -> (row rl, col-block cb): 2 threads/row, 16 cols each
    const int rl = tid >> 1, cb = (tid & 1) * 16;

    int arow;
    if (AMODE == 0) arow = m0 + rl;
    else {
        const int m = m0 + rl, q = ((m & 127) << 9) + (m >> 7);
        arow = (AMODE == 1) ? tok[q] : q;
    }
    const float* aptr = A + (size_t)arow * H;
    const int nrow = n0 + rl;
    const float* wptr = W + (size_t)nrow * H;
    const bool nok = (nrow < N);

    // wave -> 64x64 quadrant; lane -> (kg, mm)
    const int wv = tid >> 6, lane = tid & 63;
    const int mw = (wv >> 1) * 64, nw = (wv & 1) * 64;
    const int kg = lane >> 4, mm = lane & 15;

    f32x4 acc[4][4];
#pragma unroll
    for (int i = 0; i < 4; ++i)
#pragma unroll
        for (int j = 0; j < 4; ++j) acc[i][j] = (f32x4){0.f, 0.f, 0.f, 0.f};

    for (int kt = 0; kt < 10; ++kt) {
        const int kbase = kt * 32;
        float4 av[4], wvv[4];
#pragma unroll
        for (int j = 0; j < 4; ++j) {
            const int col = kbase + cb + j * 4;
            const bool kv = (col <= H - 4);          // full float4 in [0,300)
            av[j]  = kv ?        *(const float4*)(aptr + col) : make_float4(0,0,0,0);
            wvv[j] = (kv && nok) ? *(const float4*)(wptr + col) : make_float4(0,0,0,0);
        }
        __syncthreads();   // protect previous chunk's fragment reads
#pragma unroll
        for (int j = 0; j < 4; ++j) {
            const float a[4] = {av[j].x,  av[j].y,  av[j].z,  av[j].w};
            const float w[4] = {wvv[j].x, wvv[j].y, wvv[j].z, wvv[j].w};
            unsigned short ah[4], al_[4], wh[4], wl[4];
#pragma unroll
            for (int e = 0; e < 4; ++e) {
                ah[e] = bf16_rn(a[e]); al_[e] = bf16_rn(a[e] - bf16_f(ah[e]));
                wh[e] = bf16_rn(w[e]); wl[e]  = bf16_rn(w[e] - bf16_f(wh[e]));
            }
            const int cc = cb + j * 4;
            *(uint2*)&Ah[rl][cc] = make_uint2(pack2(ah[0],ah[1]),  pack2(ah[2],ah[3]));
            *(uint2*)&Al[rl][cc] = make_uint2(pack2(al_[0],al_[1]),pack2(al_[2],al_[3]));
            *(uint2*)&Wh[rl][cc] = make_uint2(pack2(wh[0],wh[1]),  pack2(wh[2],wh[3]));
            *(uint2*)&Wl[rl][cc] = make_uint2(pack2(wl[0],wl[1]),  pack2(wl[2],wl[3]));
        }
        __syncthreads();

        short8 fah[4], fal[4], fbh[4], fbl[4];
#pragma unroll
        for (int f = 0; f < 4; ++f) {
            fah[f] = *(const short8*)&Ah[mw + f*16 + mm][kg*8];
            fal[f] = *(const short8*)&Al[mw + f*16 + mm][kg*8];
            fbh[f] = *(const short8*)&Wh[nw + f*16 + mm][kg*8];
            fbl[f] = *(const short8*)&Wl[nw + f*16 + mm][kg*8];
        }
#pragma unroll
        for (int mf = 0; mf < 4; ++mf)
#pragma unroll
            for (int nf = 0; nf < 4; ++nf) {
                acc[mf][nf] = __builtin_amdgcn_mfma_f32_16x16x32_bf16(fah[mf], fbh[nf], acc[mf][nf], 0, 0, 0);
                acc[mf][nf] = __builtin_amdgcn_mfma_f32_16x16x32_bf16(fal[mf], fbh[nf], acc[mf][nf], 0, 0, 0);
                acc[mf][nf] = __builtin_amdgcn_mfma_f32_16x16x32_bf16(fah[mf], fbl[nf], acc[mf][nf], 0, 0, 0);
            }
    }

    // epilogue: D row = (lane>>4)*4 + r, col = lane&15 (m89 layout, verified r5)
    float bias[4];
#pragma unroll
    for (int nf = 0; nf < 4; ++nf) {
        const int n = n0 + nw + nf*16 + mm;
        float v = 0.f;
        if (n < N) { v = b1[n]; if (HASB2) v += b2[n]; }
        bias[nf] = v;
    }
    const int q = lane >> 4;
#pragma unroll
    for (int mf = 0; mf < 4; ++mf) {
        const int row = m0 + mw + mf*16 + q*4;
        float* orow = out + (size_t)row * N;
#pragma unroll
        for (int nf = 0; nf < 4; ++nf) {
            const int n = n0 + nw + nf*16 + mm;
            if (n < N) {
#pragma unroll
                for (int r = 0; r < 4; ++r)
                    orow[(size_t)r * N + n] = acc[mf][nf][r] + bias[nf];
            }
        }
    }
}

// ---------------------------------------------------------------------------
// Sentinel fill (data-as-flag protocol)
// ---------------------------------------------------------------------------
constexpr unsigned SENT = 0x7FB00F0Fu;   // quiet NaN payload; h in (-1,1) never NaN

__global__ __launch_bounds__(256)
void sentinel_fill(uint4* __restrict__ p, size_t n4)
{
    const uint4 s = make_uint4(SENT, SENT, SENT, SENT);
    size_t i = (size_t)blockIdx.x * blockDim.x + threadIdx.x;
    const size_t stride = (size_t)gridDim.x * blockDim.x;
    for (; i < n4; i += stride) p[i] = s;
}

// ---------------------------------------------------------------------------
// LSTM recurrence v7 = v6 with the round-5 block mapping RESTORED (the
// XCD-affine remap was the round-6 regression: FETCH dropped 3x — locality
// achieved — but hot-spotting one XCD's L2/atomic path with a whole batch
// group's poll storm cost +18%). Batched poll scan kept (its isolated effect
// is this round's A/B vs round 5's 2.99 ms).
// ---------------------------------------------------------------------------
constexpr int HGC = 15;
constexpr int BGC = 16;
constexpr int NWG = HGC * BGC;   // 240

constexpr int APAR = 20480;

template<int NT0, int NTN, bool ISW0>
__device__ void compute_wave(int lane, int hg, int bg,
                             const float* __restrict__ xg,
                             const float* __restrict__ Whh,
                             float* __restrict__ h_all,
                             unsigned char (*Abuf)[APAR],
                             float (*gd)[80], int* lflags)
{
    const int kg = lane >> 4, mm = lane & 15;

    short8 bh[10][NTN], bl[10][NTN];
#pragma unroll
    for (int kt = 0; kt < 10; ++kt) {
#pragma unroll
        for (int j = 0; j < NTN; ++j) {
            const int n    = (NT0 + j) * 16 + mm;
            const int grow = (n / 20) * H + hg * 20 + (n % 20);
            const int k0   = kt * 32 + kg * 8;
            short8 hi, lo;
#pragma unroll
            for (int qq = 0; qq < 8; ++qq) {
                const int k = k0 + qq;
                const float v = (k < H) ? Whh[(size_t)grow * H + k] : 0.f;
                const unsigned short h16 = bf16_rn(v);
                hi[qq] = (short)h16;
                lo[qq] = (short)bf16_rn(v - bf16_f(h16));
            }
            bh[kt][j] = hi; bl[kt][j] = lo;
        }
    }

    float cst[4] = {0.f, 0.f, 0.f, 0.f};

    for (int t = 0; t < T; ++t) {
        float xv[4][4];
        if (ISW0 && lane < 40) {
#pragma unroll
            for (int r = 0; r < 4; ++r) {
                const int idx = lane + 40 * r, b = idx / 20, l = idx % 20;
                const float* xb = xg + ((size_t)t * B + bg * 8 + b) * G4 + hg * 20 + l;
#pragma unroll
                for (int g = 0; g < 4; ++g) xv[r][g] = xb[g * H];
            }
        }

        if (t > 0) {
            while (__hip_atomic_load(&lflags[0], __ATOMIC_ACQUIRE,
                                     __HIP_MEMORY_SCOPE_WORKGROUP) < t ||
                   __hip_atomic_load(&lflags[1], __ATOMIC_ACQUIRE,
                                     __HIP_MEMORY_SCOPE_WORKGROUP) < t) {}
        }
        const unsigned char* Ab = Abuf[t & 1];

        f32x4 D[NTN];
#pragma unroll
        for (int j = 0; j < NTN; ++j) D[j] = (f32x4){0.f, 0.f, 0.f, 0.f};

#pragma unroll
        for (int kt = 0; kt < 10; ++kt) {
            const short8 ah = *(const short8*)(Ab + ((kt*2+0)*4 + kg)*256 + mm*16);
            const short8 al = *(const short8*)(Ab + ((kt*2+1)*4 + kg)*256 + mm*16);
#pragma unroll
            for (int j = 0; j < NTN; ++j) {
                D[j] = __builtin_amdgcn_mfma_f32_16x16x32_bf16(ah, bh[kt][j], D[j], 0, 0, 0);
                D[j] = __builtin_amdgcn_mfma_f32_16x16x32_bf16(al, bh[kt][j], D[j], 0, 0, 0);
                D[j] = __builtin_amdgcn_mfma_f32_16x16x32_bf16(ah, bl[kt][j], D[j], 0, 0, 0);
            }
        }

        if (lane < 32) {
#pragma unroll
            for (int j = 0; j < NTN; ++j)
#pragma unroll
                for (int r = 0; r < 4; ++r)
                    gd[(lane >> 4) * 4 + r][(NT0 + j) * 16 + mm] = D[j][r];
        }

        if (!ISW0) {
            __hip_atomic_store(&lflags[2], t + 1, __ATOMIC_RELEASE,
                               __HIP_MEMORY_SCOPE_WORKGROUP);
        } else {
            while (__hip_atomic_load(&lflags[2], __ATOMIC_ACQUIRE,
                                     __HIP_MEMORY_SCOPE_WORKGROUP) < t + 1) {}
            if (lane < 40) {
#pragma unroll
                for (int r = 0; r < 4; ++r) {
                    const int idx = lane + 40 * r, b = idx / 20, l = idx % 20;
                    const float gi = xv[r][0] + gd[b][     l];
                    const float gf = xv[r][1] + gd[b][20 + l];
                    const float gz = xv[r][2] + gd[b][40 + l];
                    const float go = xv[r][3] + gd[b][60 + l];
                    const float iG = sigm(gi), fG = sigm(gf);
                    const float zG = tanhfast(gz), oG = sigm(go);
                    cst[r] = fmaf(fG, cst[r], iG * zG);
                    const float hv = oG * tanhfast(cst[r]);
                    __hip_atomic_store(h_all + ((size_t)(bg*8 + b) * T + t) * H + hg*20 + l,
                                       hv, __ATOMIC_RELAXED, __HIP_MEMORY_SCOPE_AGENT);
                }
            }
        }
    }
}

__device__ void poller_wave(int pw, int lane, int bg,
                            const float* __restrict__ h_all,
                            unsigned char (*Abuf)[APAR], int* lflags)
{
    const int pl = pw * 64 + lane;         // 0..127
    const float* qbase[3]; int offh[3], offl[3]; unsigned pend0 = 0; bool qok[3];
#pragma unroll
    for (int q = 0; q < 3; ++q) {
        const int s = pl + 128 * q;
        qok[q] = (s < 304);
        if (qok[q]) {
            const int b = s / 38, kq = s % 38;
            qbase[q] = h_all + (size_t)(bg*8 + b) * T * H + kq * 8;
            const int kt = kq >> 2, kgq = kq & 3;
            offh[q] = ((kt*2 + 0)*4 + kgq)*256 + b*16;
            offl[q] = ((kt*2 + 1)*4 + kgq)*256 + b*16;
            pend0 |= ((kq < 37) ? 0xFu : 0x3u) << (4*q);
        } else { qbase[q] = h_all; offh[q] = offl[q] = 0; }
    }

    for (int pt = 1; pt < T; ++pt) {
        float v[3][8];
#pragma unroll
        for (int q = 0; q < 3; ++q)
#pragma unroll
            for (int e = 0; e < 8; ++e) v[q][e] = 0.f;

        unsigned pend = pend0;
        const size_t toff = (size_t)(pt - 1) * H;
        while (__any(pend != 0)) {
            // issue ALL pending loads back-to-back, then check (scan ~ 1 RT)
            unsigned long long w[3][4];
#pragma unroll
            for (int q = 0; q < 3; ++q)
#pragma unroll
                for (int j2 = 0; j2 < 4; ++j2)
                    if (pend & (1u << (4*q + j2)))
                        w[q][j2] = __hip_atomic_load(
                            (const unsigned long long*)(qbase[q] + toff) + j2,
                            __ATOMIC_RELAXED, __HIP_MEMORY_SCOPE_AGENT);
#pragma unroll
            for (int q = 0; q < 3; ++q)
#pragma unroll
                for (int j2 = 0; j2 < 4; ++j2) {
                    const unsigned bit = 1u << (4*q + j2);
                    if (pend & bit) {
                        const unsigned long long x = w[q][j2];
                        if ((unsigned)x != SENT && (unsigned)(x >> 32) != SENT) {
                            v[q][2*j2]   = __uint_as_float((unsigned)x);
                            v[q][2*j2+1] = __uint_as_float((unsigned)(x >> 32));
                            pend &= ~bit;
                        }
                    }
                }
        }

        unsigned char* Ap = Abuf[pt & 1];
#pragma unroll
        for (int q = 0; q < 3; ++q) {
            if (qok[q]) {
                unsigned short h16[8]; uint4 hi, lo;
#pragma unroll
                for (int e = 0; e < 8; ++e) h16[e] = bf16_rn(v[q][e]);
                hi.x = pack2(h16[0], h16[1]); hi.y = pack2(h16[2], h16[3]);
                hi.z = pack2(h16[4], h16[5]); hi.w = pack2(h16[6], h16[7]);
                unsigned short l16[8];
#pragma unroll
                for (int e = 0; e < 8; ++e)
                    l16[e] = bf16_rn(v[q][e] - bf16_f(h16[e]));
                lo.x = pack2(l16[0], l16[1]); lo.y = pack2(l16[2], l16[3]);
                lo.z = pack2(l16[4], l16[5]); lo.w = pack2(l16[6], l16[7]);
                *(uint4*)(Ap + offh[q]) = hi;
                *(uint4*)(Ap + offl[q]) = lo;
            }
        }
        if (lane == 0)
            __hip_atomic_store(&lflags[pw], pt, __ATOMIC_RELEASE,
                               __HIP_MEMORY_SCOPE_WORKGROUP);
    }
}

__global__ __launch_bounds__(256, 1)
void lstm_mfma_k(const float* __restrict__ xg, const float* __restrict__ Whh,
                 float* __restrict__ h_all)
{
    __shared__ __align__(16) unsigned char Abuf[2][APAR];   // 40 KiB
    __shared__ __align__(16) float gd[8][80];
    __shared__ int lflags[16];

    const int tid = threadIdx.x, wv = tid >> 6, lane = tid & 63;
    // round-5 mapping restored (round-6 XCD-affine remap regressed)
    const int hg = blockIdx.x % HGC, bg = blockIdx.x / HGC;

    for (int i = tid; i < 2 * APAR / 16; i += 256)
        ((uint4*)Abuf)[i] = make_uint4(0, 0, 0, 0);
    if (tid < 16) lflags[tid] = 0;
    __syncthreads();

    if      (wv == 0) compute_wave<0, 3, true >(lane, hg, bg, xg, Whh, h_all, Abuf, gd, lflags);
    else if (wv == 1) compute_wave<3, 2, false>(lane, hg, bg, xg, Whh, h_all, Abuf, gd, lflags);
    else              poller_wave(wv - 2, lane, bg, h_all, Abuf, lflags);
}

} // anonymous namespace

// ---------------------------------------------------------------------------
extern "C" void kernel_launch(void* const* d_in, const int* in_sizes, int n_in,
                              void* d_out, int out_size, void* d_ws, size_t ws_size,
                              hipStream_t stream)
{
    const int*   x    = (const int*)  d_in[0];
    const float* emb  = (const float*)d_in[1];
    const float* Wih0 = (const float*)d_in[2];
    const float* Whh0 = (const float*)d_in[3];
    const float* bih0 = (const float*)d_in[4];
    const float* bhh0 = (const float*)d_in[5];
    const float* Wih1 = (const float*)d_in[6];
    const float* Whh1 = (const float*)d_in[7];
    const float* bih1 = (const float*)d_in[8];
    const float* bhh1 = (const float*)d_in[9];
    const float* Wout = (const float*)d_in[10];
    const float* bout = (const float*)d_in[11];

    float* out = (float*)d_out;
    // xg [T][B][4H] fp32 (315 MB) aliases the output buffer (659 MB): fully
    // consumed before the final GEMM overwrites d_out.
    float* xg = (float*)d_out;
    float* h1 = (float*)d_ws;                       // [B][T][H] fp32, 78.6 MB
    float* h2 = h1 + (size_t)B * T * H;             // 78.6 MB

    // sentinel-fill both h buffers (data-as-flag protocol)
    const size_t nh = 2 * (size_t)B * T * H;
    sentinel_fill<<<dim3(2048), dim3(256), 0, stream>>>((uint4*)h1, nh / 4);

    const dim3 blk(256);
    // L0 input projection (embedding gather fused), MFMA split-precision
    gemm_mfma<1, true ><<<dim3(10, 512), blk, 0, stream>>>(emb, Wih0, bih0, bhh0, x, xg, G4);
    // L0 recurrence
    lstm_mfma_k<<<dim3(NWG), blk, 0, stream>>>(xg, Whh0, h1);
    // L1 input projection ([b][t] -> [t][b] permute fused)
    gemm_mfma<2, true ><<<dim3(10, 512), blk, 0, stream>>>(h1, Wih1, bih1, bhh1, nullptr, xg, G4);
    // L1 recurrence
    lstm_mfma_k<<<dim3(NWG), blk, 0, stream>>>(xg, Whh1, h2);
    // output projection -> logits [b*T+t][NVOC]
    gemm_mfma<0, false><<<dim3(20, 512), blk, 0, stream>>>(h2, Wout, bout, nullptr, nullptr, out, NVOC);
}

// Round 8
// 4319.927 us; speedup vs baseline: 2.2186x; 1.7019x over previous
//
#include <hip/hip_runtime.h>
#include <cstdint>
#include <cstddef>

namespace {

constexpr int H    = 300;
constexpr int G4   = 1200;   // 4*H
constexpr int B    = 128;
constexpr int T    = 512;
constexpr int NVOC = 2514;

typedef __attribute__((ext_vector_type(8))) short  short8;
typedef __attribute__((ext_vector_type(4))) float  f32x4;

__device__ __forceinline__ float sigm(float x)     { return 1.f / (1.f + __expf(-x)); }
__device__ __forceinline__ float tanhfast(float x) { return 1.f - 2.f / (__expf(2.f*x) + 1.f); }

__device__ __forceinline__ unsigned short bf16_rn(float f) {
    unsigned u = __float_as_uint(f);
    u += 0x7FFFu + ((u >> 16) & 1u);
    return (unsigned short)(u >> 16);
}
__device__ __forceinline__ float bf16_f(unsigned short s) {
    return __uint_as_float(((unsigned)s) << 16);
}
__device__ __forceinline__ unsigned pack2(unsigned short lo16, unsigned short hi16) {
    return (unsigned)lo16 | ((unsigned)hi16 << 16);
}

// ---------------------------------------------------------------------------
// MFMA split-precision GEMM (unchanged from round 7 — passed, ~1.4 ms total)
// ---------------------------------------------------------------------------
template<int AMODE, bool HASB2>
__global__ __launch_bounds__(256)
void gemm_mfma(const float* __restrict__ A, const float* __restrict__ W,
               const float* __restrict__ b1, const float* __restrict__ b2,
               const int* __restrict__ tok, float* __restrict__ out, int N)
{
    __shared__ __align__(16) unsigned short Ah[128][40], Al[128][40];
    __shared__ __align__(16) unsigned short Wh[128][40], Wl[128][40];

    const int tid = threadIdx.x;
    const int m0 = blockIdx.y * 128, n0 = blockIdx.x * 128;
    const int rl = tid >> 1, cb = (tid & 1) * 16;

    int arow;
    if (AMODE == 0) arow = m0 + rl;
    else {
        const int m = m0 + rl, q = ((m & 127) << 9) + (m >> 7);
        arow = (AMODE == 1) ? tok[q] : q;
    }
    const float* aptr = A + (size_t)arow * H;
    const int nrow = n0 + rl;
    const float* wptr = W + (size_t)nrow * H;
    const bool nok = (nrow < N);

    const int wv = tid >> 6, lane = tid & 63;
    const int mw = (wv >> 1) * 64, nw = (wv & 1) * 64;
    const int kg = lane >> 4, mm = lane & 15;

    f32x4 acc[4][4];
#pragma unroll
    for (int i = 0; i < 4; ++i)
#pragma unroll
        for (int j = 0; j < 4; ++j) acc[i][j] = (f32x4){0.f, 0.f, 0.f, 0.f};

    for (int kt = 0; kt < 10; ++kt) {
        const int kbase = kt * 32;
        float4 av[4], wvv[4];
#pragma unroll
        for (int j = 0; j < 4; ++j) {
            const int col = kbase + cb + j * 4;
            const bool kv = (col <= H - 4);
            av[j]  = kv ?        *(const float4*)(aptr + col) : make_float4(0,0,0,0);
            wvv[j] = (kv && nok) ? *(const float4*)(wptr + col) : make_float4(0,0,0,0);
        }
        __syncthreads();
#pragma unroll
        for (int j = 0; j < 4; ++j) {
            const float a[4] = {av[j].x,  av[j].y,  av[j].z,  av[j].w};
            const float w[4] = {wvv[j].x, wvv[j].y, wvv[j].z, wvv[j].w};
            unsigned short ah[4], al_[4], wh[4], wl[4];
#pragma unroll
            for (int e = 0; e < 4; ++e) {
                ah[e] = bf16_rn(a[e]); al_[e] = bf16_rn(a[e] - bf16_f(ah[e]));
                wh[e] = bf16_rn(w[e]); wl[e]  = bf16_rn(w[e] - bf16_f(wh[e]));
            }
            const int cc = cb + j * 4;
            *(uint2*)&Ah[rl][cc] = make_uint2(pack2(ah[0],ah[1]),  pack2(ah[2],ah[3]));
            *(uint2*)&Al[rl][cc] = make_uint2(pack2(al_[0],al_[1]),pack2(al_[2],al_[3]));
            *(uint2*)&Wh[rl][cc] = make_uint2(pack2(wh[0],wh[1]),  pack2(wh[2],wh[3]));
            *(uint2*)&Wl[rl][cc] = make_uint2(pack2(wl[0],wl[1]),  pack2(wl[2],wl[3]));
        }
        __syncthreads();

        short8 fah[4], fal[4], fbh[4], fbl[4];
#pragma unroll
        for (int f = 0; f < 4; ++f) {
            fah[f] = *(const short8*)&Ah[mw + f*16 + mm][kg*8];
            fal[f] = *(const short8*)&Al[mw + f*16 + mm][kg*8];
            fbh[f] = *(const short8*)&Wh[nw + f*16 + mm][kg*8];
            fbl[f] = *(const short8*)&Wl[nw + f*16 + mm][kg*8];
        }
#pragma unroll
        for (int mf = 0; mf < 4; ++mf)
#pragma unroll
            for (int nf = 0; nf < 4; ++nf) {
                acc[mf][nf] = __builtin_amdgcn_mfma_f32_16x16x32_bf16(fah[mf], fbh[nf], acc[mf][nf], 0, 0, 0);
                acc[mf][nf] = __builtin_amdgcn_mfma_f32_16x16x32_bf16(fal[mf], fbh[nf], acc[mf][nf], 0, 0, 0);
                acc[mf][nf] = __builtin_amdgcn_mfma_f32_16x16x32_bf16(fah[mf], fbl[nf], acc[mf][nf], 0, 0, 0);
            }
    }

    float bias[4];
#pragma unroll
    for (int nf = 0; nf < 4; ++nf) {
        const int n = n0 + nw + nf*16 + mm;
        float v = 0.f;
        if (n < N) { v = b1[n]; if (HASB2) v += b2[n]; }
        bias[nf] = v;
    }
    const int q = lane >> 4;
#pragma unroll
    for (int mf = 0; mf < 4; ++mf) {
        const int row = m0 + mw + mf*16 + q*4;
        float* orow = out + (size_t)row * N;
#pragma unroll
        for (int nf = 0; nf < 4; ++nf) {
            const int n = n0 + nw + nf*16 + mm;
            if (n < N) {
#pragma unroll
                for (int r = 0; r < 4; ++r)
                    orow[(size_t)r * N + n] = acc[mf][nf][r] + bias[nf];
            }
        }
    }
}

// ---------------------------------------------------------------------------
// Sentinel fill (data-as-flag protocol)
// ---------------------------------------------------------------------------
constexpr unsigned SENT = 0x7FB00F0Fu;   // quiet NaN payload; h in (-1,1) never NaN

__global__ __launch_bounds__(256)
void sentinel_fill(uint4* __restrict__ p, size_t n4)
{
    const uint4 s = make_uint4(SENT, SENT, SENT, SENT);
    size_t i = (size_t)blockIdx.x * blockDim.x + threadIdx.x;
    const size_t stride = (size_t)gridDim.x * blockDim.x;
    for (; i < n4; i += stride) p[i] = s;
}

// ---------------------------------------------------------------------------
// LSTM recurrence v8 — SYMMETRIC self-staging waves, zero intra-block flags.
// 240 blocks = 15 hg x 16 bg; 4 identical peer waves per block.
// Unit-major gate reorder: local col c = u_loc*4 + gate -> each 16-col MFMA
// n-tile holds 4 COMPLETE units, so the wave that computes a tile also does
// its activations/cell/h-store with no cross-wave exchange.
// Per wave per step:
//   1. poll its K-quarter of h[t-1] (batched 8B relaxed agent atomics vs
//      sentinel; 5 slots/lane; quarters disjoint -> no duplicate traffic)
//   2. cvt to bf16 hi/lo, ds_write A-fragments (MFMA layout, double-buffered)
//   3. __syncthreads (the ONLY per-step sync)
//   4. 10 kt x (1|2 nt) x 3-pass MFMA with B-frags resident in VGPRs
//   5. wave-local gd spill (same-wave LDS, lgkmcnt-ordered), activations,
//      private cell state, per-lane 4B h store (relaxed agent)
// Removed vs v7: poller->compute LDS flag, wave1->wave0 gd flag, and both
// wake-up latencies. Wave roles: w0 = nt{0,1} (units 0-7), w1/w2/w3 = nt
// 2/3/4 (units 8-11/12-15/16-19); poll quarter = wave id.
// ---------------------------------------------------------------------------
constexpr int HGC = 15;
constexpr int BGC = 16;
constexpr int NWG = HGC * BGC;   // 240
constexpr int APAR = 20480;      // A-frag bytes per parity

__global__ __launch_bounds__(256, 1)
void lstm_v8(const float* __restrict__ xg, const float* __restrict__ Whh,
             float* __restrict__ h_all)
{
    __shared__ __align__(16) unsigned char Abuf[2][APAR];   // 40 KiB
    __shared__ __align__(16) float gd[5][8][16];            // per-nt D spill

    const int tid = threadIdx.x, wv = tid >> 6, lane = tid & 63;
    const int hg = blockIdx.x % HGC, bg = blockIdx.x / HGC;

    // zero both A parities (t=0 state h[-1]=0 + permanent k/m padding)
    for (int i = tid; i < 2 * APAR / 16; i += 256)
        ((uint4*)Abuf)[i] = make_uint4(0, 0, 0, 0);
    __syncthreads();

    const int kg = lane >> 4, mm = lane & 15;
    const int NT0 = (wv == 0) ? 0 : wv + 1;   // first n-tile of this wave
    const int NTN = (wv == 0) ? 2 : 1;        // n-tiles owned
    const int sh  = (wv == 0) ? 3 : 2;        // log2(units owned)

    // ---- one-time: B fragments (hi/lo bf16) in VGPRs, unit-major columns ---
    short8 bh[10][2], bl[10][2];
#pragma unroll
    for (int kt = 0; kt < 10; ++kt)
#pragma unroll
        for (int j = 0; j < 2; ++j) {
            const int c    = (NT0 + j) * 16 + mm;            // local col
            const int grow = (c & 3) * H + hg * 20 + (c >> 2); // gate-major row
            const int k0   = kt * 32 + kg * 8;
            short8 hi, lo;
#pragma unroll
            for (int q = 0; q < 8; ++q) {
                const int k = k0 + q;
                const float v = (j < NTN && k < H) ? Whh[(size_t)grow * H + k] : 0.f;
                const unsigned short h16 = bf16_rn(v);
                hi[q] = (short)h16;
                lo[q] = (short)bf16_rn(v - bf16_f(h16));
            }
            bh[kt][j] = hi; bl[kt][j] = lo;
        }

    // ---- poll slots: 304 8B-pairs per K-quarter, 5 slots/lane ----
    size_t prow[5]; int offh_[5], offl_[5]; unsigned pend0 = 0;
#pragma unroll
    for (int j = 0; j < 5; ++j) {
        const int s = lane + 64 * j;
        const int b = s / 38, kp = s % 38;
        const int k = wv * 76 + kp * 2;
        const bool ok = (s < 304) && (k < 300);
        if (ok) pend0 |= 1u << j;
        prow[j] = (size_t)(bg * 8 + (ok ? b : 0)) * T * H + (ok ? k : 0);
        const int kt = k >> 5, kq = (k >> 3) & 3, pos = k & 7;
        offh_[j] = ((kt * 2 + 0) * 4 + kq) * 256 + b * 16 + pos * 2;
        offl_[j] = offh_[j] + 1024;
    }

    // ---- update mapping: lane -> (batch row, owned unit) ----
    const bool upd   = lane < (NTN << 5);
    const int  b_u   = lane >> sh;
    const int  u4    = lane & ((1 << sh) - 1);
    const int  u_loc = NT0 * 4 + u4;
    const int  nt_l  = NT0 + (u4 >> 2);
    const int  u_rel = u4 & 3;
    float cst = 0.f;

    const float* xb0 = xg + (size_t)(bg * 8 + b_u) * G4 + hg * 20 + u_loc;
    float* hst = h_all + (size_t)(bg * 8 + b_u) * T * H + hg * 20 + u_loc;

    for (int t = 0; t < T; ++t) {
        // xg prefetch (issues early; consumed after the barrier)
        float xv0 = 0.f, xv1 = 0.f, xv2 = 0.f, xv3 = 0.f;
        if (upd) {
            const float* xb = xb0 + (size_t)t * B * G4;
            xv0 = xb[0]; xv1 = xb[H]; xv2 = xb[2 * H]; xv3 = xb[3 * H];
        }

        if (t > 0) {
            // ---- batched poll of our K-quarter of h[t-1] ----
            unsigned long long val[5];
            unsigned pend = pend0;
            const size_t tadd = (size_t)(t - 1) * H;
            while (__any(pend != 0)) {
                unsigned long long w[5];
#pragma unroll
                for (int j = 0; j < 5; ++j)
                    if (pend & (1u << j))
                        w[j] = __hip_atomic_load(
                            (const unsigned long long*)(h_all + prow[j] + tadd),
                            __ATOMIC_RELAXED, __HIP_MEMORY_SCOPE_AGENT);
#pragma unroll
                for (int j = 0; j < 5; ++j) {
                    if (pend & (1u << j)) {
                        const unsigned long long x = w[j];
                        if ((unsigned)x != SENT && (unsigned)(x >> 32) != SENT) {
                            val[j] = x; pend &= ~(1u << j);
                        }
                    }
                }
            }
            // ---- cvt + A-fragment writes (hi & lo planes) ----
            unsigned char* Ap = Abuf[t & 1];
#pragma unroll
            for (int j = 0; j < 5; ++j)
                if (pend0 & (1u << j)) {
                    const float v0 = __uint_as_float((unsigned)val[j]);
                    const float v1 = __uint_as_float((unsigned)(val[j] >> 32));
                    const unsigned short h0 = bf16_rn(v0), h1 = bf16_rn(v1);
                    *(unsigned*)(Ap + offh_[j]) = pack2(h0, h1);
                    *(unsigned*)(Ap + offl_[j]) =
                        pack2(bf16_rn(v0 - bf16_f(h0)), bf16_rn(v1 - bf16_f(h1)));
                }
        }
        __syncthreads();   // the only per-step sync

        // ---- MFMA: A from LDS, B resident; 3-pass split precision ----
        const unsigned char* Ab = Abuf[t & 1];
        f32x4 a0 = (f32x4){0.f, 0.f, 0.f, 0.f};
        f32x4 a1 = (f32x4){0.f, 0.f, 0.f, 0.f};
#pragma unroll
        for (int kt = 0; kt < 10; ++kt) {
            const short8 ah = *(const short8*)(Ab + ((kt*2+0)*4 + kg)*256 + mm*16);
            const short8 al = *(const short8*)(Ab + ((kt*2+1)*4 + kg)*256 + mm*16);
            a0 = __builtin_amdgcn_mfma_f32_16x16x32_bf16(ah, bh[kt][0], a0, 0, 0, 0);
            a0 = __builtin_amdgcn_mfma_f32_16x16x32_bf16(al, bh[kt][0], a0, 0, 0, 0);
            a0 = __builtin_amdgcn_mfma_f32_16x16x32_bf16(ah, bl[kt][0], a0, 0, 0, 0);
            if (NTN > 1) {
                a1 = __builtin_amdgcn_mfma_f32_16x16x32_bf16(ah, bh[kt][1], a1, 0, 0, 0);
                a1 = __builtin_amdgcn_mfma_f32_16x16x32_bf16(al, bh[kt][1], a1, 0, 0, 0);
                a1 = __builtin_amdgcn_mfma_f32_16x16x32_bf16(ah, bl[kt][1], a1, 0, 0, 0);
            }
        }

        // ---- wave-local D spill (same-wave LDS, in-order) ----
        if (lane < 32) {
            const int br = (lane >> 4) * 4;
#pragma unroll
            for (int r = 0; r < 4; ++r) gd[NT0][br + r][mm] = a0[r];
            if (NTN > 1)
#pragma unroll
                for (int r = 0; r < 4; ++r) gd[NT0 + 1][br + r][mm] = a1[r];
        }

        // ---- activations + cell + h publish (own units only) ----
        if (upd) {
            const float* g4 = &gd[nt_l][b_u][u_rel * 4];
            const float gi = xv0 + g4[0], gf = xv1 + g4[1];
            const float gz = xv2 + g4[2], go = xv3 + g4[3];
            const float iG = sigm(gi), fG = sigm(gf);
            const float zG = tanhfast(gz), oG = sigm(go);
            cst = fmaf(fG, cst, iG * zG);
            const float hv = oG * tanhfast(cst);
            __hip_atomic_store(hst + (size_t)t * H, hv,
                               __ATOMIC_RELAXED, __HIP_MEMORY_SCOPE_AGENT);
        }
    }
}

} // anonymous namespace

// ---------------------------------------------------------------------------
extern "C" void kernel_launch(void* const* d_in, const int* in_sizes, int n_in,
                              void* d_out, int out_size, void* d_ws, size_t ws_size,
                              hipStream_t stream)
{
    const int*   x    = (const int*)  d_in[0];
    const float* emb  = (const float*)d_in[1];
    const float* Wih0 = (const float*)d_in[2];
    const float* Whh0 = (const float*)d_in[3];
    const float* bih0 = (const float*)d_in[4];
    const float* bhh0 = (const float*)d_in[5];
    const float* Wih1 = (const float*)d_in[6];
    const float* Whh1 = (const float*)d_in[7];
    const float* bih1 = (const float*)d_in[8];
    const float* bhh1 = (const float*)d_in[9];
    const float* Wout = (const float*)d_in[10];
    const float* bout = (const float*)d_in[11];

    float* out = (float*)d_out;
    // xg [T][B][4H] fp32 (315 MB) aliases the output buffer (659 MB): fully
    // consumed before the final GEMM overwrites d_out.
    float* xg = (float*)d_out;
    float* h1 = (float*)d_ws;                       // [B][T][H] fp32, 78.6 MB
    float* h2 = h1 + (size_t)B * T * H;             // 78.6 MB

    // sentinel-fill both h buffers (data-as-flag protocol)
    const size_t nh = 2 * (size_t)B * T * H;
    sentinel_fill<<<dim3(2048), dim3(256), 0, stream>>>((uint4*)h1, nh / 4);

    const dim3 blk(256);
    // L0 input projection (embedding gather fused), MFMA split-precision
    gemm_mfma<1, true ><<<dim3(10, 512), blk, 0, stream>>>(emb, Wih0, bih0, bhh0, x, xg, G4);
    // L0 recurrence
    lstm_v8<<<dim3(NWG), blk, 0, stream>>>(xg, Whh0, h1);
    // L1 input projection ([b][t] -> [t][b] permute fused)
    gemm_mfma<2, true ><<<dim3(10, 512), blk, 0, stream>>>(h1, Wih1, bih1, bhh1, nullptr, xg, G4);
    // L1 recurrence
    lstm_v8<<<dim3(NWG), blk, 0, stream>>>(xg, Whh1, h2);
    // output projection -> logits [b*T+t][NVOC]
    gemm_mfma<0, false><<<dim3(20, 512), blk, 0, stream>>>(h2, Wout, bout, nullptr, nullptr, out, NVOC);
}

// Round 9
// 3969.316 us; speedup vs baseline: 2.4145x; 1.0883x over previous
//
#include <hip/hip_runtime.h>
#include <cstdint>
#include <cstddef>

namespace {

constexpr int H    = 300;
constexpr int G4   = 1200;   // 4*H
constexpr int B    = 128;
constexpr int T    = 512;
constexpr int NVOC = 2514;

typedef __attribute__((ext_vector_type(8))) short  short8;
typedef __attribute__((ext_vector_type(4))) float  f32x4;

__device__ __forceinline__ float sigm(float x)     { return 1.f / (1.f + __expf(-x)); }
__device__ __forceinline__ float tanhfast(float x) { return 1.f - 2.f / (__expf(2.f*x) + 1.f); }

__device__ __forceinline__ unsigned short bf16_rn(float f) {
    unsigned u = __float_as_uint(f);
    u += 0x7FFFu + ((u >> 16) & 1u);
    return (unsigned short)(u >> 16);
}
__device__ __forceinline__ float bf16_f(unsigned short s) {
    return __uint_as_float(((unsigned)s) << 16);
}
__device__ __forceinline__ unsigned pack2(unsigned short lo16, unsigned short hi16) {
    return (unsigned)lo16 | ((unsigned)hi16 << 16);
}

// ---------------------------------------------------------------------------
// MFMA split-precision GEMM (unchanged from round 7; used for xg0 and logits)
// ---------------------------------------------------------------------------
template<int AMODE, bool HASB2>
__global__ __launch_bounds__(256)
void gemm_mfma(const float* __restrict__ A, const float* __restrict__ W,
               const float* __restrict__ b1, const float* __restrict__ b2,
               const int* __restrict__ tok, float* __restrict__ out, int N)
{
    __shared__ __align__(16) unsigned short Ah[128][40], Al[128][40];
    __shared__ __align__(16) unsigned short Wh[128][40], Wl[128][40];

    const int tid = threadIdx.x;
    const int m0 = blockIdx.y * 128, n0 = blockIdx.x * 128;
    const int rl = tid >> 1, cb = (tid & 1) * 16;

    int arow;
    if (AMODE == 0) arow = m0 + rl;
    else {
        const int m = m0 + rl, q = ((m & 127) << 9) + (m >> 7);
        arow = (AMODE == 1) ? tok[q] : q;
    }
    const float* aptr = A + (size_t)arow * H;
    const int nrow = n0 + rl;
    const float* wptr = W + (size_t)nrow * H;
    const bool nok = (nrow < N);

    const int wv = tid >> 6, lane = tid & 63;
    const int mw = (wv >> 1) * 64, nw = (wv & 1) * 64;
    const int kg = lane >> 4, mm = lane & 15;

    f32x4 acc[4][4];
#pragma unroll
    for (int i = 0; i < 4; ++i)
#pragma unroll
        for (int j = 0; j < 4; ++j) acc[i][j] = (f32x4){0.f, 0.f, 0.f, 0.f};

    for (int kt = 0; kt < 10; ++kt) {
        const int kbase = kt * 32;
        float4 av[4], wvv[4];
#pragma unroll
        for (int j = 0; j < 4; ++j) {
            const int col = kbase + cb + j * 4;
            const bool kv = (col <= H - 4);
            av[j]  = kv ?        *(const float4*)(aptr + col) : make_float4(0,0,0,0);
            wvv[j] = (kv && nok) ? *(const float4*)(wptr + col) : make_float4(0,0,0,0);
        }
        __syncthreads();
#pragma unroll
        for (int j = 0; j < 4; ++j) {
            const float a[4] = {av[j].x,  av[j].y,  av[j].z,  av[j].w};
            const float w[4] = {wvv[j].x, wvv[j].y, wvv[j].z, wvv[j].w};
            unsigned short ah[4], al_[4], wh[4], wl[4];
#pragma unroll
            for (int e = 0; e < 4; ++e) {
                ah[e] = bf16_rn(a[e]); al_[e] = bf16_rn(a[e] - bf16_f(ah[e]));
                wh[e] = bf16_rn(w[e]); wl[e]  = bf16_rn(w[e] - bf16_f(wh[e]));
            }
            const int cc = cb + j * 4;
            *(uint2*)&Ah[rl][cc] = make_uint2(pack2(ah[0],ah[1]),  pack2(ah[2],ah[3]));
            *(uint2*)&Al[rl][cc] = make_uint2(pack2(al_[0],al_[1]),pack2(al_[2],al_[3]));
            *(uint2*)&Wh[rl][cc] = make_uint2(pack2(wh[0],wh[1]),  pack2(wh[2],wh[3]));
            *(uint2*)&Wl[rl][cc] = make_uint2(pack2(wl[0],wl[1]),  pack2(wl[2],wl[3]));
        }
        __syncthreads();

        short8 fah[4], fal[4], fbh[4], fbl[4];
#pragma unroll
        for (int f = 0; f < 4; ++f) {
            fah[f] = *(const short8*)&Ah[mw + f*16 + mm][kg*8];
            fal[f] = *(const short8*)&Al[mw + f*16 + mm][kg*8];
            fbh[f] = *(const short8*)&Wh[nw + f*16 + mm][kg*8];
            fbl[f] = *(const short8*)&Wl[nw + f*16 + mm][kg*8];
        }
#pragma unroll
        for (int mf = 0; mf < 4; ++mf)
#pragma unroll
            for (int nf = 0; nf < 4; ++nf) {
                acc[mf][nf] = __builtin_amdgcn_mfma_f32_16x16x32_bf16(fah[mf], fbh[nf], acc[mf][nf], 0, 0, 0);
                acc[mf][nf] = __builtin_amdgcn_mfma_f32_16x16x32_bf16(fal[mf], fbh[nf], acc[mf][nf], 0, 0, 0);
                acc[mf][nf] = __builtin_amdgcn_mfma_f32_16x16x32_bf16(fah[mf], fbl[nf], acc[mf][nf], 0, 0, 0);
            }
    }

    float bias[4];
#pragma unroll
    for (int nf = 0; nf < 4; ++nf) {
        const int n = n0 + nw + nf*16 + mm;
        float v = 0.f;
        if (n < N) { v = b1[n]; if (HASB2) v += b2[n]; }
        bias[nf] = v;
    }
    const int q = lane >> 4;
#pragma unroll
    for (int mf = 0; mf < 4; ++mf) {
        const int row = m0 + mw + mf*16 + q*4;
        float* orow = out + (size_t)row * N;
#pragma unroll
        for (int nf = 0; nf < 4; ++nf) {
            const int n = n0 + nw + nf*16 + mm;
            if (n < N) {
#pragma unroll
                for (int r = 0; r < 4; ++r)
                    orow[(size_t)r * N + n] = acc[mf][nf][r] + bias[nf];
            }
        }
    }
}

// ---------------------------------------------------------------------------
// Sentinel fill (data-as-flag protocol)
// ---------------------------------------------------------------------------
constexpr unsigned SENT = 0x7FB00F0Fu;   // quiet NaN payload; h in (-1,1) never NaN

__global__ __launch_bounds__(256)
void sentinel_fill(uint4* __restrict__ p, size_t n4)
{
    const uint4 s = make_uint4(SENT, SENT, SENT, SENT);
    size_t i = (size_t)blockIdx.x * blockDim.x + threadIdx.x;
    const size_t stride = (size_t)gridDim.x * blockDim.x;
    for (; i < n4; i += stride) p[i] = s;
}

// ---------------------------------------------------------------------------
// v9 — FUSED two-layer LSTM. 240 blocks (15 hg x 16 bg), 512 threads = 8 waves.
// Iteration it (0..T): L0 computes h1[it] from h1[it-1]; L1 computes h2[it-1]
// from h1[it-1] (feed-forward, SAME staged fragments) and h2[it-2].
// 513 visibility rounds instead of 1024, and the xg1 GEMM vanishes (Wih1
// folded into the per-step MFMA).
// Waves 0-2: gates0 tiles {0,1},{2,3},{4} (Whh0 frags resident) + L0 update.
// Waves 3-7: gates1 tile (wv-3) (Wih1+Whh1 frags resident, 160 VGPR) + L1
//            update. Poll duty: wv0-3 = h1 quarters, wv4-7 = h2 quarters
//            (v8 batched data-as-flag polls). One __syncthreads per iteration.
// LDS: A-frags {h1, h2} x {hi,lo} double-buffered = 80 KiB + gd 5 KiB.
// Deadlock-free: iteration it only waits on publishes from iteration it-1,
// which occur unconditionally; all 240 blocks co-resident (1/CU, LDS-bound).
// ---------------------------------------------------------------------------
constexpr int HGC = 15;
constexpr int BGC = 16;
constexpr int NWG = HGC * BGC;   // 240
constexpr int A2OFF = 20480;     // h2 A-region offset within a parity
constexpr int APARF = 40960;     // bytes per parity (h1 + h2 regions)
constexpr int GDOFF = 2 * APARF; // gd spill offset
constexpr int FLDS  = GDOFF + 10 * 8 * 16 * 4;   // 87040 B

struct PollCtx {
    size_t   prow[5];
    int      offh[5];
    unsigned pend0;
};

__device__ __forceinline__ void poll_init(PollCtx& P, int lane, int quarter,
                                          int bg, int regionOff)
{
    P.pend0 = 0;
#pragma unroll
    for (int j = 0; j < 5; ++j) {
        const int s = lane + 64 * j;
        const int b = (s < 304) ? s / 38 : 0, kp = (s < 304) ? s % 38 : 0;
        const int k = quarter * 76 + kp * 2;
        const bool ok = (s < 304) && (k < 300);
        if (ok) P.pend0 |= 1u << j;
        P.prow[j] = (size_t)(bg * 8 + b) * T * H + (ok ? k : 0);
        const int kt = k >> 5, kq = (k >> 3) & 3, pos = k & 7;
        P.offh[j] = regionOff + ((kt * 2 + 0) * 4 + kq) * 256 + b * 16 + pos * 2;
    }
}

__device__ __forceinline__ void poll_stage(const PollCtx& P,
                                           const float* __restrict__ src,
                                           size_t tadd, unsigned char* Ap)
{
    unsigned long long val[5] = {0, 0, 0, 0, 0};
    unsigned pend = P.pend0;
    while (__any(pend != 0)) {
        unsigned long long w[5];
#pragma unroll
        for (int j = 0; j < 5; ++j)
            if (pend & (1u << j))
                w[j] = __hip_atomic_load(
                    (const unsigned long long*)(src + P.prow[j] + tadd),
                    __ATOMIC_RELAXED, __HIP_MEMORY_SCOPE_AGENT);
#pragma unroll
        for (int j = 0; j < 5; ++j)
            if (pend & (1u << j)) {
                const unsigned long long x = w[j];
                if ((unsigned)x != SENT && (unsigned)(x >> 32) != SENT) {
                    val[j] = x; pend &= ~(1u << j);
                }
            }
    }
#pragma unroll
    for (int j = 0; j < 5; ++j)
        if (P.pend0 & (1u << j)) {
            const float v0 = __uint_as_float((unsigned)val[j]);
            const float v1 = __uint_as_float((unsigned)(val[j] >> 32));
            const unsigned short h0 = bf16_rn(v0), h1b = bf16_rn(v1);
            *(unsigned*)(Ap + P.offh[j]) = pack2(h0, h1b);
            *(unsigned*)(Ap + P.offh[j] + 1024) =
                pack2(bf16_rn(v0 - bf16_f(h0)), bf16_rn(v1 - bf16_f(h1b)));
        }
}

// ---- gates0 waves: Whh0-resident MFMA + L0 cell update + h1 publish ----
template<int NTN>
__device__ void fused_g0(int lane, int hg, int bg, int NT0, int quarter,
                         const float* __restrict__ xg0,
                         const float* __restrict__ Whh0,
                         float* __restrict__ h1,
                         unsigned char* __restrict__ Abuf,
                         float (*gd)[8][16])
{
    const int kg = lane >> 4, mm = lane & 15;

    short8 bh[10][NTN], bl[10][NTN];
#pragma unroll
    for (int kt = 0; kt < 10; ++kt)
#pragma unroll
        for (int j = 0; j < NTN; ++j) {
            const int c = (NT0 + j) * 16 + mm;
            const int grow = (c & 3) * H + hg * 20 + (c >> 2);
            short8 hi, lo;
#pragma unroll
            for (int q = 0; q < 8; ++q) {
                const int k = kt * 32 + kg * 8 + q;
                const float v = (k < H) ? Whh0[(size_t)grow * H + k] : 0.f;
                const unsigned short h16 = bf16_rn(v);
                hi[q] = (short)h16;
                lo[q] = (short)bf16_rn(v - bf16_f(h16));
            }
            bh[kt][j] = hi; bl[kt][j] = lo;
        }

    PollCtx P; poll_init(P, lane, quarter, bg, 0);

    const int sh = (NTN == 2) ? 3 : 2;
    const bool upd = lane < (NTN << 5);
    const int b_u = lane >> sh, u4 = lane & ((1 << sh) - 1);
    const int u_loc = NT0 * 4 + u4;
    const int ntl = NT0 + (u4 >> 2), u_rel = u4 & 3;
    float cst = 0.f;

    const float* xb0 = xg0 + (size_t)(bg * 8 + b_u) * G4 + hg * 20 + u_loc;
    float* hst = h1 + (size_t)(bg * 8 + b_u) * T * H + hg * 20 + u_loc;

    for (int it = 0; it <= T; ++it) {
        float xv0 = 0.f, xv1 = 0.f, xv2 = 0.f, xv3 = 0.f;
        if (upd && it < T) {
            const float* xb = xb0 + (size_t)it * B * G4;
            xv0 = xb[0]; xv1 = xb[H]; xv2 = xb[2 * H]; xv3 = xb[3 * H];
        }
        unsigned char* Ap = Abuf + (it & 1) * APARF;
        if (it >= 1) poll_stage(P, h1, (size_t)(it - 1) * H, Ap);
        __syncthreads();

        if (it < T) {
            f32x4 a0 = (f32x4){0.f,0.f,0.f,0.f}, a1 = (f32x4){0.f,0.f,0.f,0.f};
#pragma unroll
            for (int kt = 0; kt < 10; ++kt) {
                const short8 ah = *(const short8*)(Ap + ((kt*2+0)*4 + kg)*256 + mm*16);
                const short8 al = *(const short8*)(Ap + ((kt*2+1)*4 + kg)*256 + mm*16);
                a0 = __builtin_amdgcn_mfma_f32_16x16x32_bf16(ah, bh[kt][0], a0, 0, 0, 0);
                a0 = __builtin_amdgcn_mfma_f32_16x16x32_bf16(al, bh[kt][0], a0, 0, 0, 0);
                a0 = __builtin_amdgcn_mfma_f32_16x16x32_bf16(ah, bl[kt][0], a0, 0, 0, 0);
                if (NTN > 1) {
                    a1 = __builtin_amdgcn_mfma_f32_16x16x32_bf16(ah, bh[kt][1], a1, 0, 0, 0);
                    a1 = __builtin_amdgcn_mfma_f32_16x16x32_bf16(al, bh[kt][1], a1, 0, 0, 0);
                    a1 = __builtin_amdgcn_mfma_f32_16x16x32_bf16(ah, bl[kt][1], a1, 0, 0, 0);
                }
            }
            if (lane < 32) {
                const int br = (lane >> 4) * 4;
#pragma unroll
                for (int r = 0; r < 4; ++r) gd[NT0][br + r][mm] = a0[r];
                if (NTN > 1)
#pragma unroll
                    for (int r = 0; r < 4; ++r) gd[NT0 + 1][br + r][mm] = a1[r];
            }
            if (upd) {
                const float* g4 = &gd[ntl][b_u][u_rel * 4];
                const float gi = xv0 + g4[0], gf = xv1 + g4[1];
                const float gz = xv2 + g4[2], go = xv3 + g4[3];
                const float iG = sigm(gi), fG = sigm(gf);
                const float zG = tanhfast(gz), oG = sigm(go);
                cst = fmaf(fG, cst, iG * zG);
                const float hv = oG * tanhfast(cst);
                __hip_atomic_store(hst + (size_t)it * H, hv,
                                   __ATOMIC_RELAXED, __HIP_MEMORY_SCOPE_AGENT);
            }
        }
    }
}

// ---- gates1 waves: Wih1+Whh1-resident MFMA + L1 cell update + h2 publish ---
__device__ void fused_g1(int lane, int hg, int bg, int ntg,
                         const float* __restrict__ psrc, int pdelta,
                         int regionOff, int quarter,
                         const float* __restrict__ Wih1,
                         const float* __restrict__ Whh1,
                         const float* __restrict__ bih1,
                         const float* __restrict__ bhh1,
                         float* __restrict__ h2,
                         unsigned char* __restrict__ Abuf,
                         float (*gd)[8][16])
{
    const int kg = lane >> 4, mm = lane & 15;
    const int c = ntg * 16 + mm;
    const int grow = (c & 3) * H + hg * 20 + (c >> 2);

    short8 bIh[10], bIl[10], bHh[10], bHl[10];
#pragma unroll
    for (int kt = 0; kt < 10; ++kt) {
        short8 ih, il, hh, hl;
#pragma unroll
        for (int q = 0; q < 8; ++q) {
            const int k = kt * 32 + kg * 8 + q;
            const float vi = (k < H) ? Wih1[(size_t)grow * H + k] : 0.f;
            const float vh = (k < H) ? Whh1[(size_t)grow * H + k] : 0.f;
            const unsigned short i16 = bf16_rn(vi), h16 = bf16_rn(vh);
            ih[q] = (short)i16; il[q] = (short)bf16_rn(vi - bf16_f(i16));
            hh[q] = (short)h16; hl[q] = (short)bf16_rn(vh - bf16_f(h16));
        }
        bIh[kt] = ih; bIl[kt] = il; bHh[kt] = hh; bHl[kt] = hl;
    }

    PollCtx P; poll_init(P, lane, quarter, bg, regionOff);

    const bool upd = lane < 32;
    const int b_u = lane >> 2, u4 = lane & 3;
    const int u_loc = ntg * 4 + u4;
    float bias[4];
#pragma unroll
    for (int g = 0; g < 4; ++g) {
        const int gr = g * H + hg * 20 + u_loc;
        bias[g] = bih1[gr] + bhh1[gr];
    }
    float cst = 0.f;
    float* hst = h2 + (size_t)(bg * 8 + b_u) * T * H + hg * 20 + u_loc;

    for (int it = 0; it <= T; ++it) {
        unsigned char* Ap = Abuf + (it & 1) * APARF;
        if (it >= pdelta) poll_stage(P, psrc, (size_t)(it - pdelta) * H, Ap);
        __syncthreads();

        if (it >= 1) {
            f32x4 acc = (f32x4){0.f, 0.f, 0.f, 0.f};
#pragma unroll
            for (int kt = 0; kt < 10; ++kt) {   // h1[it-1] @ Wih1^T
                const short8 ah = *(const short8*)(Ap + ((kt*2+0)*4 + kg)*256 + mm*16);
                const short8 al = *(const short8*)(Ap + ((kt*2+1)*4 + kg)*256 + mm*16);
                acc = __builtin_amdgcn_mfma_f32_16x16x32_bf16(ah, bIh[kt], acc, 0, 0, 0);
                acc = __builtin_amdgcn_mfma_f32_16x16x32_bf16(al, bIh[kt], acc, 0, 0, 0);
                acc = __builtin_amdgcn_mfma_f32_16x16x32_bf16(ah, bIl[kt], acc, 0, 0, 0);
            }
#pragma unroll
            for (int kt = 0; kt < 10; ++kt) {   // h2[it-2] @ Whh1^T
                const short8 ah = *(const short8*)(Ap + A2OFF + ((kt*2+0)*4 + kg)*256 + mm*16);
                const short8 al = *(const short8*)(Ap + A2OFF + ((kt*2+1)*4 + kg)*256 + mm*16);
                acc = __builtin_amdgcn_mfma_f32_16x16x32_bf16(ah, bHh[kt], acc, 0, 0, 0);
                acc = __builtin_amdgcn_mfma_f32_16x16x32_bf16(al, bHh[kt], acc, 0, 0, 0);
                acc = __builtin_amdgcn_mfma_f32_16x16x32_bf16(ah, bHl[kt], acc, 0, 0, 0);
            }
            if (lane < 32) {
                const int br = (lane >> 4) * 4;
#pragma unroll
                for (int r = 0; r < 4; ++r) gd[5 + ntg][br + r][mm] = acc[r];
            }
            if (upd) {
                const float* g4 = &gd[5 + ntg][b_u][u4 * 4];
                const float gi = bias[0] + g4[0], gf = bias[1] + g4[1];
                const float gz = bias[2] + g4[2], go = bias[3] + g4[3];
                const float iG = sigm(gi), fG = sigm(gf);
                const float zG = tanhfast(gz), oG = sigm(go);
                cst = fmaf(fG, cst, iG * zG);
                const float hv = oG * tanhfast(cst);
                __hip_atomic_store(hst + (size_t)(it - 1) * H, hv,
                                   __ATOMIC_RELAXED, __HIP_MEMORY_SCOPE_AGENT);
            }
        }
    }
}

__global__ __launch_bounds__(512)
void lstm_fused(const float* __restrict__ xg0,
                const float* __restrict__ Whh0,
                const float* __restrict__ Wih1,
                const float* __restrict__ Whh1,
                const float* __restrict__ bih1,
                const float* __restrict__ bhh1,
                float* __restrict__ h1, float* __restrict__ h2)
{
    extern __shared__ unsigned char smem[];
    unsigned char* Abuf = smem;                              // [2][40960]
    float (*gd)[8][16] = (float(*)[8][16])(smem + GDOFF);    // [10][8][16]

    const int tid = threadIdx.x, wv = tid >> 6, lane = tid & 63;
    const int hg = blockIdx.x % HGC, bg = blockIdx.x / HGC;

    // zero all LDS: A parities (h[-1]=0, h2[-1]=0, k/m padding) + gd
    for (int i = tid; i < FLDS / 16; i += 512)
        ((uint4*)smem)[i] = make_uint4(0, 0, 0, 0);
    __syncthreads();

    if      (wv == 0) fused_g0<2>(lane, hg, bg, 0, 0, xg0, Whh0, h1, Abuf, gd);
    else if (wv == 1) fused_g0<2>(lane, hg, bg, 2, 1, xg0, Whh0, h1, Abuf, gd);
    else if (wv == 2) fused_g0<1>(lane, hg, bg, 4, 2, xg0, Whh0, h1, Abuf, gd);
    else if (wv == 3) fused_g1(lane, hg, bg, 0, h1, 1, 0,     3,      Wih1, Whh1, bih1, bhh1, h2, Abuf, gd);
    else              fused_g1(lane, hg, bg, wv - 3, h2, 2, A2OFF, wv - 4, Wih1, Whh1, bih1, bhh1, h2, Abuf, gd);
}

} // anonymous namespace

// ---------------------------------------------------------------------------
extern "C" void kernel_launch(void* const* d_in, const int* in_sizes, int n_in,
                              void* d_out, int out_size, void* d_ws, size_t ws_size,
                              hipStream_t stream)
{
    const int*   x    = (const int*)  d_in[0];
    const float* emb  = (const float*)d_in[1];
    const float* Wih0 = (const float*)d_in[2];
    const float* Whh0 = (const float*)d_in[3];
    const float* bih0 = (const float*)d_in[4];
    const float* bhh0 = (const float*)d_in[5];
    const float* Wih1 = (const float*)d_in[6];
    const float* Whh1 = (const float*)d_in[7];
    const float* bih1 = (const float*)d_in[8];
    const float* bhh1 = (const float*)d_in[9];
    const float* Wout = (const float*)d_in[10];
    const float* bout = (const float*)d_in[11];

    float* out = (float*)d_out;
    // xg0 [T][B][4H] fp32 (315 MB) aliases the output buffer (659 MB): fully
    // consumed by lstm_fused before the final GEMM overwrites d_out.
    float* xg = (float*)d_out;
    float* h1 = (float*)d_ws;                       // [B][T][H] fp32, 78.6 MB
    float* h2 = h1 + (size_t)B * T * H;             // 78.6 MB

    // sentinel-fill both h buffers (data-as-flag protocol)
    const size_t nh = 2 * (size_t)B * T * H;
    sentinel_fill<<<dim3(2048), dim3(256), 0, stream>>>((uint4*)h1, nh / 4);

    hipFuncSetAttribute(reinterpret_cast<const void*>(lstm_fused),
                        hipFuncAttributeMaxDynamicSharedMemorySize, FLDS);

    const dim3 blk(256);
    // L0 input projection (embedding gather fused), MFMA split-precision
    gemm_mfma<1, true ><<<dim3(10, 512), blk, 0, stream>>>(emb, Wih0, bih0, bhh0, x, xg, G4);
    // fused two-layer recurrence (xg1 GEMM folded in)
    lstm_fused<<<dim3(NWG), dim3(512), FLDS, stream>>>(xg, Whh0, Wih1, Whh1,
                                                       bih1, bhh1, h1, h2);
    // output projection -> logits [b*T+t][NVOC]
    gemm_mfma<0, false><<<dim3(20, 512), blk, 0, stream>>>(h2, Wout, bout, nullptr, nullptr, out, NVOC);
}